// Round 4
// baseline (560.481 us; speedup 1.0000x reference)
//
#include <hip/hip_runtime.h>

#define NROWS 32768
#define DIM   1024
#define HIDD  512
#define M3    (3*NROWS)

using bf16x8 = __attribute__((ext_vector_type(8))) short;
using f32x4  = __attribute__((ext_vector_type(4))) float;

#define MFMA16(a,b,c) __builtin_amdgcn_mfma_f32_16x16x32_bf16(a,b,c,0,0,0)
#define WAIT_VM(N)  asm volatile("s_waitcnt vmcnt(" #N ")" ::: "memory")
#define WAIT_LGKM0  asm volatile("s_waitcnt lgkmcnt(0)" ::: "memory")
#define MEMFENCE    asm volatile("" ::: "memory")
#define BAR()       __builtin_amdgcn_s_barrier()
#define SCHEDB()    __builtin_amdgcn_sched_barrier(0)

// ---------- helpers ----------
static __device__ __forceinline__ unsigned short f2bf(float f) {
    unsigned u = __float_as_uint(f);
    u += 0x7FFFu + ((u >> 16) & 1u);   // round-to-nearest-even
    return (unsigned short)(u >> 16);
}
static __device__ __forceinline__ unsigned cvtpk(float a, float b) {
    unsigned r;
    asm("v_cvt_pk_bf16_f32 %0, %1, %2" : "=v"(r) : "v"(a), "v"(b));
    return r;
}
static __device__ __forceinline__ void gload16(const void* gsrc, void* ldst) {
    __builtin_amdgcn_global_load_lds(
        (const __attribute__((address_space(1))) unsigned int*)gsrc,
        (__attribute__((address_space(3))) unsigned int*)ldst,
        16, 0, 0);
}

// ---------- convert fp32 -> bf16 (for W1, W2) ----------
__global__ __launch_bounds__(256)
void cvt_kernel(const float* __restrict__ src, unsigned short* __restrict__ dst, int n4)
{
    const int i = blockIdx.x * 256 + threadIdx.x;
    if (i < n4) {
        float4 v = reinterpret_cast<const float4*>(src)[i];
        uint2 o;
        o.x = cvtpk(v.x, v.y);
        o.y = cvtpk(v.z, v.w);
        reinterpret_cast<uint2*>(dst)[i] = o;
    }
}

// ---------- GEMM1 (MFMA, pipelined): h = leaky(bn(x @ W1^T + b1)), h bf16 [3N][512] ----------
// 3072 blocks XCD-swizzled. 128x128 tile, BK=64, 4 waves each own 64x64 (4x4 frags).
// Counted-vmcnt pipeline: B prefetch distance 2 (gload_lds dbuf), A distance 2 in regs, staged dist 1.
__global__ __launch_bounds__(256)
void gemm1_mfma(const float* __restrict__ x0, const float* __restrict__ x1,
                const float* __restrict__ x2,
                const unsigned short* __restrict__ W1bf,
                const float* __restrict__ b1, const float* __restrict__ gamma,
                const float* __restrict__ beta, const float* __restrict__ rmean,
                const float* __restrict__ rvar,
                unsigned short* __restrict__ h)
{
    __shared__ char smem[65536];                 // A dbuf 2x16384 | B dbuf 2x16384
    char* const Ab0 = smem;
    char* const Bb0 = smem + 32768;

    const int lin = blockIdx.x;                  // 3072 = 8 XCD * 384
    const int wgid = (lin & 7) * 384 + (lin >> 3);
    const int cb = wgid & 3;
    const int rb = wgid >> 2;
    const int tid  = threadIdx.x;
    const int lane = tid & 63, w = tid >> 6;
    const int wr = w >> 1, wc = w & 1;
    const int row0 = rb * 128;
    const int s = row0 >> 15;
    const float* x = (s == 0) ? x0 : (s == 1 ? x1 : x2);
    const int rl0 = row0 & (NROWS - 1);
    const int col0 = cb * 128;
    const int l15 = lane & 15, lq = lane >> 4;

    f32x4 acc[4][4] = {};
    float4 aR[8];

    // ---- prologue: B(0), aR(0), B(1) issued; stage A(0); issue aR(1) ----
    #pragma unroll
    for (int c = 0; c < 4; ++c) {                // B(0) -> Bb[0]
        const int f = c * 256 + tid;
        const int panel = f >> 9, cc = (f >> 2) & 127;
        const int chunk = (f & 3) ^ ((cc >> 1) & 3);
        gload16(&W1bf[(size_t)(col0 + cc) * DIM + panel * 32 + chunk * 8], Bb0 + f * 16);
    }
    MEMFENCE;
    #pragma unroll
    for (int p = 0; p < 8; ++p) {                // aR(0)
        const int f = p * 256 + tid, r = f >> 4, c4 = f & 15;
        aR[p] = *reinterpret_cast<const float4*>(&x[(size_t)(rl0 + r) * DIM + c4 * 4]);
    }
    MEMFENCE;
    #pragma unroll
    for (int c = 0; c < 4; ++c) {                // B(1) -> Bb[1]
        const int f = c * 256 + tid;
        const int panel = f >> 9, cc = (f >> 2) & 127;
        const int chunk = (f & 3) ^ ((cc >> 1) & 3);
        gload16(&W1bf[(size_t)(col0 + cc) * DIM + 64 + panel * 32 + chunk * 8], Bb0 + 16384 + f * 16);
    }
    WAIT_VM(4);                                  // B(0)+aR(0) done; B(1) in flight
    #pragma unroll
    for (int p = 0; p < 8; ++p) {                // stage A(0) -> Ab[0]
        const int f = p * 256 + tid, r = f >> 4, c4 = f & 15;
        const unsigned off = (unsigned)((r * 128 + c4 * 8) ^ ((r & 7) << 4));
        uint2 o; o.x = cvtpk(aR[p].x, aR[p].y); o.y = cvtpk(aR[p].z, aR[p].w);
        *reinterpret_cast<uint2*>(Ab0 + off) = o;
    }
    MEMFENCE;
    #pragma unroll
    for (int p = 0; p < 8; ++p) {                // aR(1)
        const int f = p * 256 + tid, r = f >> 4, c4 = f & 15;
        aR[p] = *reinterpret_cast<const float4*>(&x[(size_t)(rl0 + r) * DIM + 64 + c4 * 4]);
    }
    WAIT_LGKM0;
    BAR();
    SCHEDB();

    for (int t = 0; t < 16; ++t) {
        const int k0 = t * 64;
        char* const At = Ab0 + (t & 1) * 16384;
        char* const An = Ab0 + ((t & 1) ^ 1) * 16384;
        char* const Bt = Bb0 + (t & 1) * 16384;
        const int kf = (k0 + 128 < 1024) ? (k0 + 128) : 960;   // clamped prefetch K

        // (A1) kk=0 frags
        bf16x8 af[4], bfv[4];
        #pragma unroll
        for (int m = 0; m < 4; ++m) {
            const int row = wr * 64 + m * 16 + l15;
            af[m] = *reinterpret_cast<const bf16x8*>(At + ((row * 128 + lq * 16) ^ ((row & 7) << 4)));
        }
        #pragma unroll
        for (int n = 0; n < 4; ++n) {
            const int colr = wc * 64 + n * 16 + l15;
            bfv[n] = *reinterpret_cast<const bf16x8*>(Bt + colr * 64 + (lq ^ ((colr >> 1) & 3)) * 16);
        }
        // (H1) kk=0 MFMAs
        #pragma unroll
        for (int m = 0; m < 4; ++m)
            #pragma unroll
            for (int n = 0; n < 4; ++n)
                acc[m][n] = MFMA16(af[m], bfv[n], acc[m][n]);
        // (A2) kk=1 frags
        bf16x8 af2[4], bfv2[4];
        #pragma unroll
        for (int m = 0; m < 4; ++m) {
            const int row = wr * 64 + m * 16 + l15;
            af2[m] = *reinterpret_cast<const bf16x8*>(At + ((row * 128 + 64 + lq * 16) ^ ((row & 7) << 4)));
        }
        #pragma unroll
        for (int n = 0; n < 4; ++n) {
            const int colr = wc * 64 + n * 16 + l15;
            bfv2[n] = *reinterpret_cast<const bf16x8*>(Bt + 8192 + colr * 64 + (lq ^ ((colr >> 1) & 3)) * 16);
        }
        WAIT_LGKM0;       // own reads complete
        BAR();            // all waves done reading bufs[t&1]
        SCHEDB();
        // (D) issue B(t+2) -> Bt (parity t&1)
        #pragma unroll
        for (int c = 0; c < 4; ++c) {
            const int f = c * 256 + tid;
            const int panel = f >> 9, cc = (f >> 2) & 127;
            const int chunk = (f & 3) ^ ((cc >> 1) & 3);
            gload16(&W1bf[(size_t)(col0 + cc) * DIM + kf + panel * 32 + chunk * 8], Bt + f * 16);
        }
        // (E) aR(t+1) + B(t+1) drained; B(t+2) stays in flight
        WAIT_VM(4);
        // (F) stage A(t+1) -> An
        #pragma unroll
        for (int p = 0; p < 8; ++p) {
            const int f = p * 256 + tid, r = f >> 4, c4 = f & 15;
            const unsigned off = (unsigned)((r * 128 + c4 * 8) ^ ((r & 7) << 4));
            uint2 o; o.x = cvtpk(aR[p].x, aR[p].y); o.y = cvtpk(aR[p].z, aR[p].w);
            *reinterpret_cast<uint2*>(An + off) = o;
        }
        MEMFENCE;
        // (G) issue aR(t+2)
        #pragma unroll
        for (int p = 0; p < 8; ++p) {
            const int f = p * 256 + tid, r = f >> 4, c4 = f & 15;
            aR[p] = *reinterpret_cast<const float4*>(&x[(size_t)(rl0 + r) * DIM + kf + c4 * 4]);
        }
        // (H2) kk=1 MFMAs (cover outstanding loads)
        #pragma unroll
        for (int m = 0; m < 4; ++m)
            #pragma unroll
            for (int n = 0; n < 4; ++n)
                acc[m][n] = MFMA16(af2[m], bfv2[n], acc[m][n]);
        WAIT_LGKM0;       // own A-stage writes complete
        BAR();            // bufs[(t+1)&1] ready for next iter
        SCHEDB();
    }
    asm volatile("s_waitcnt vmcnt(0)" ::: "memory");   // drain tail prefetches before exit

    // epilogue: BN(eval) + leaky folded to v*A + B per column
    float As[4], Bsc[4];
    #pragma unroll
    for (int n = 0; n < 4; ++n) {
        const int c = col0 + wc * 64 + n * 16 + l15;
        const float inv = rsqrtf(rvar[c] + 1e-5f);
        As[n]  = inv * gamma[c];
        Bsc[n] = (b1[c] - rmean[c]) * As[n] + beta[c];
    }
    #pragma unroll
    for (int m = 0; m < 4; ++m) {
        const int rbase = row0 + wr * 64 + m * 16 + lq * 4;
        #pragma unroll
        for (int n = 0; n < 4; ++n) {
            const int c = col0 + wc * 64 + n * 16 + l15;
            #pragma unroll
            for (int i = 0; i < 4; ++i) {
                float v = fmaf(acc[m][n][i], As[n], Bsc[n]);
                v = (v >= 0.f) ? v : 0.1f * v;
                h[(size_t)(rbase + i) * HIDD + c] = f2bf(v);
            }
        }
    }
}

// ---------- GEMM2 (MFMA, fused, pipelined): e = h @ W2^T + b2 for a/p/n; distances + L2 ----------
// 4096 blocks XCD-swizzled; 64 batch-rows x 128 cols x 3 streams, BK=32, 256 thr / 4 waves.
// Wave wv owns cols [wv*32, wv*32+32), all 64 rows, 3 streams. Counted-vmcnt pipeline dist 2.
__global__ __launch_bounds__(256)
void gemm2_mfma(const unsigned short* __restrict__ h,
                const unsigned short* __restrict__ W2bf,
                const float* __restrict__ b2,
                float* __restrict__ pdp, float* __restrict__ pdn,
                float* __restrict__ pl2)
{
    __shared__ char smem[40960];                 // A dbuf 2x12288 | B dbuf 2x8192
    char* const Ab0 = smem;
    char* const Bb0 = smem + 24576;

    const int lin = blockIdx.x;                  // 4096 = 8 * 512
    const int wgid = (lin & 7) * 512 + (lin >> 3);
    const int cb = wgid & 7;
    const int rb = wgid >> 3;
    const int tid  = threadIdx.x;
    const int lane = tid & 63, wv = tid >> 6;    // 4 waves = col quarters
    const int row0 = rb * 64;
    const int col0 = cb * 128;
    const int l15 = lane & 15, lq = lane >> 4;

    f32x4 acc[3][4][2] = {};                     // [stream][m][n]

    // staging: 5 gloads/thread (3 A + 2 B)
    #define G2_STAGE(KF, ABASE, BBASE)                                                    \
        do {                                                                              \
            _Pragma("unroll")                                                             \
            for (int i_ = 0; i_ < 3; ++i_) {                                              \
                const int f_ = i_ * 256 + tid;                                            \
                const int ss_ = f_ >> 8;                                                  \
                const int r_  = (f_ >> 2) & 63;                                           \
                const int ch_ = (f_ & 3) ^ ((r_ >> 1) & 3);                               \
                gload16(&h[((size_t)ss_ * NROWS + row0 + r_) * HIDD + (KF) + ch_ * 8],    \
                        (ABASE) + f_ * 16);                                               \
            }                                                                             \
            _Pragma("unroll")                                                             \
            for (int i_ = 0; i_ < 2; ++i_) {                                              \
                const int f_ = i_ * 256 + tid;                                            \
                const int cc_ = f_ >> 2;                                                  \
                const int ch_ = (f_ & 3) ^ ((cc_ >> 1) & 3);                              \
                gload16(&W2bf[(size_t)(col0 + cc_) * HIDD + (KF) + ch_ * 8],              \
                        (BBASE) + f_ * 16);                                               \
            }                                                                             \
        } while (0)

    // ---- prologue ----
    G2_STAGE(0, Ab0, Bb0);
    MEMFENCE;
    G2_STAGE(32, Ab0 + 12288, Bb0 + 8192);
    WAIT_VM(5);                                  // batch(0) drained, batch(1) in flight
    BAR();
    SCHEDB();

    for (int t = 0; t < 16; ++t) {
        const int k0 = t * 32;
        char* const At = Ab0 + (t & 1) * 12288;
        char* const Bt = Bb0 + (t & 1) * 8192;
        const int kf = (k0 + 64 < 512) ? (k0 + 64) : 480;

        // (A1) B frags + A frags m=0,1
        bf16x8 b1v[2], a1[3][2], a2[3][2];
        #pragma unroll
        for (int n = 0; n < 2; ++n) {
            const int colr = wv * 32 + n * 16 + l15;
            b1v[n] = *reinterpret_cast<const bf16x8*>(Bt + colr * 64 + (lq ^ ((colr >> 1) & 3)) * 16);
        }
        #pragma unroll
        for (int ss = 0; ss < 3; ++ss)
            #pragma unroll
            for (int m = 0; m < 2; ++m) {
                const int r = m * 16 + l15;
                a1[ss][m] = *reinterpret_cast<const bf16x8*>(At + ss * 4096 + r * 64 + (lq ^ ((r >> 1) & 3)) * 16);
            }
        // (H1) m=0,1 MFMAs
        #pragma unroll
        for (int ss = 0; ss < 3; ++ss)
            #pragma unroll
            for (int m = 0; m < 2; ++m) {
                acc[ss][m][0] = MFMA16(a1[ss][m], b1v[0], acc[ss][m][0]);
                acc[ss][m][1] = MFMA16(a1[ss][m], b1v[1], acc[ss][m][1]);
            }
        // (A2) A frags m=2,3
        #pragma unroll
        for (int ss = 0; ss < 3; ++ss)
            #pragma unroll
            for (int m = 0; m < 2; ++m) {
                const int r = (m + 2) * 16 + l15;
                a2[ss][m] = *reinterpret_cast<const bf16x8*>(At + ss * 4096 + r * 64 + (lq ^ ((r >> 1) & 3)) * 16);
            }
        WAIT_LGKM0;
        BAR();            // all waves done reading bufs[t&1]
        SCHEDB();
        // (D) issue batch(t+2) into bufs[t&1]
        G2_STAGE(kf, At, Bt);
        // (H2) m=2,3 MFMAs (cover the wait)
        #pragma unroll
        for (int ss = 0; ss < 3; ++ss)
            #pragma unroll
            for (int m = 0; m < 2; ++m) {
                acc[ss][m + 2][0] = MFMA16(a2[ss][m], b1v[0], acc[ss][m + 2][0]);
                acc[ss][m + 2][1] = MFMA16(a2[ss][m], b1v[1], acc[ss][m + 2][1]);
            }
        WAIT_VM(5);       // batch(t+1) drained; batch(t+2) in flight
        BAR();
        SCHEDB();
    }

    __syncthreads();      // full drain (incl. tail prefetch) before LDS reuse

    // epilogue: distances + L2, never materializing e
    float* const dpred = (float*)smem;           // [4][64]
    float* const dnred = (float*)(smem + 1024);  // [4][64]
    float* const l2red = (float*)(smem + 2048);  // [4]
    float b2c[2];
    b2c[0] = b2[col0 + wv * 32 + l15];
    b2c[1] = b2[col0 + wv * 32 + 16 + l15];
    float l2t = 0.f;
    #pragma unroll
    for (int m = 0; m < 4; ++m) {
        #pragma unroll
        for (int i = 0; i < 4; ++i) {
            float dp = 0.f, dn = 0.f;
            #pragma unroll
            for (int n = 0; n < 2; ++n) {
                const float ea = acc[0][m][n][i] + b2c[n];
                const float ep = acc[1][m][n][i] + b2c[n];
                const float en = acc[2][m][n][i] + b2c[n];
                dp += (ea - ep) * (ea - ep);
                dn += (ea - en) * (ea - en);
                l2t += ea * ea + ep * ep + en * en;
            }
            #pragma unroll
            for (int mm = 1; mm < 16; mm <<= 1) {
                dp += __shfl_xor(dp, mm);
                dn += __shfl_xor(dn, mm);
            }
            if (l15 == 0) {
                dpred[wv * 64 + m * 16 + lq * 4 + i] = dp;
                dnred[wv * 64 + m * 16 + lq * 4 + i] = dn;
            }
        }
    }
    #pragma unroll
    for (int mm = 1; mm < 64; mm <<= 1) l2t += __shfl_xor(l2t, mm);
    if (lane == 0) l2red[wv] = l2t;
    __syncthreads();
    if (tid < 64) {
        float dp = 0.f, dn = 0.f;
        #pragma unroll
        for (int ww = 0; ww < 4; ++ww) { dp += dpred[ww * 64 + tid]; dn += dnred[ww * 64 + tid]; }
        pdp[(size_t)cb * NROWS + row0 + tid] = dp;
        pdn[(size_t)cb * NROWS + row0 + tid] = dn;
    }
    if (tid == 0)
        pl2[(size_t)rb * 8 + cb] = l2red[0] + l2red[1] + l2red[2] + l2red[3];
}

// ---------- per-row margins ----------
__global__ __launch_bounds__(256)
void margins_kernel(const float* __restrict__ pdp, const float* __restrict__ pdn,
                    float* __restrict__ margins, float* __restrict__ dd)
{
    const int r = blockIdx.x * 256 + threadIdx.x;
    float dp2 = 0.f, dn2 = 0.f;
    #pragma unroll
    for (int cb = 0; cb < 8; ++cb) {
        dp2 += pdp[(size_t)cb * NROWS + r];
        dn2 += pdn[(size_t)cb * NROWS + r];
    }
    dd[r] = dn2 - dp2;
    margins[r] = (dn2 < dp2) ? (sqrtf(dp2) - sqrtf(dn2)) : 0.f;
}

// ---------- final: l2 sum + radix-select quantile + loss ----------
__global__ __launch_bounds__(1024)
void final_kernel(const float* __restrict__ pl2, int npl2,
                  const float* __restrict__ margins, const float* __restrict__ dd,
                  float* __restrict__ out)
{
    __shared__ unsigned hist[256];
    __shared__ float warp_red[16];
    __shared__ unsigned sh_prefix;
    __shared__ int sh_k;
    __shared__ float sh_l2;
    const int tid = threadIdx.x;

    float l2 = 0.f;
    for (int i = tid; i < npl2; i += 1024) l2 += pl2[i];
    #pragma unroll
    for (int m = 1; m < 64; m <<= 1) l2 += __shfl_xor(l2, m);
    if ((tid & 63) == 0) warp_red[tid >> 6] = l2;
    __syncthreads();
    if (tid == 0) {
        float t = 0.f;
        for (int w = 0; w < 16; ++w) t += warp_red[w];
        sh_l2 = t;
    }
    __syncthreads();

    float vsel[2];
    for (int sel = 0; sel < 2; ++sel) {
        if (tid == 0) { sh_k = 8191 + sel; sh_prefix = 0u; }
        __syncthreads();
        for (int shift = 24; shift >= 0; shift -= 8) {
            if (tid < 256) hist[tid] = 0u;
            __syncthreads();
            const unsigned prefix = sh_prefix;
            const unsigned mask = (shift == 24) ? 0u : (0xFFFFFFFFu << (shift + 8));
            for (int i = tid; i < NROWS; i += 1024) {
                const unsigned key = __float_as_uint(margins[i]);
                if (((key ^ prefix) & mask) == 0u)
                    atomicAdd(&hist[(key >> shift) & 255u], 1u);
            }
            __syncthreads();
            if (tid == 0) {
                int kk = sh_k;
                unsigned cum = 0; int d = 0;
                for (; d < 256; ++d) {
                    const unsigned c = hist[d];
                    if (cum + c > (unsigned)kk) break;
                    cum += c;
                }
                sh_prefix = prefix | ((unsigned)d << shift);
                sh_k = kk - (int)cum;
            }
            __syncthreads();
        }
        vsel[sel] = __uint_as_float(sh_prefix);
        __syncthreads();
    }
    const float margin = vsel[0] + 0.75f * (vsel[1] - vsel[0]);

    float ssum = 0.f;
    for (int i = tid; i < NROWS; i += 1024) {
        const float t = dd[i] + margin;
        ssum += (t > 0.f) ? t : 0.f;
    }
    #pragma unroll
    for (int m = 1; m < 64; m <<= 1) ssum += __shfl_xor(ssum, m);
    if ((tid & 63) == 0) warp_red[tid >> 6] = ssum;
    __syncthreads();
    if (tid == 0) {
        float S = 0.f;
        for (int w = 0; w < 16; ++w) S += warp_red[w];
        out[0] = S / (float)NROWS + 1e-3f * sh_l2 / (float)NROWS;
    }
}

extern "C" void kernel_launch(void* const* d_in, const int* in_sizes, int n_in,
                              void* d_out, int out_size, void* d_ws, size_t ws_size,
                              hipStream_t stream) {
    (void)in_sizes; (void)n_in; (void)out_size; (void)ws_size;
    const float* item = (const float*)d_in[0];
    const float* pos  = (const float*)d_in[1];
    const float* neg  = (const float*)d_in[2];
    const float* W1   = (const float*)d_in[3];
    const float* b1   = (const float*)d_in[4];
    const float* gam  = (const float*)d_in[5];
    const float* bet  = (const float*)d_in[6];
    const float* rmu  = (const float*)d_in[7];
    const float* rvr  = (const float*)d_in[8];
    const float* W2   = (const float*)d_in[9];
    const float* b2   = (const float*)d_in[10];

    char* ws = (char*)d_ws;
    unsigned short* h = (unsigned short*)ws;
    size_t off = (size_t)M3 * HIDD * sizeof(unsigned short);
    unsigned short* W1bf = (unsigned short*)(ws + off); off += (size_t)HIDD * DIM * 2;
    unsigned short* W2bf = (unsigned short*)(ws + off); off += (size_t)DIM * HIDD * 2;
    float* pdp = (float*)(ws + off); off += (size_t)8 * NROWS * 4;
    float* pdn = (float*)(ws + off); off += (size_t)8 * NROWS * 4;
    float* pl2 = (float*)(ws + off); off += (size_t)4096 * 4;
    float* margins = (float*)(ws + off); off += (size_t)NROWS * 4;
    float* dd = (float*)(ws + off); off += (size_t)NROWS * 4;

    cvt_kernel<<<dim3((HIDD*DIM/4 + 255)/256), 256, 0, stream>>>(W1, W1bf, HIDD*DIM/4);
    cvt_kernel<<<dim3((DIM*HIDD/4 + 255)/256), 256, 0, stream>>>(W2, W2bf, DIM*HIDD/4);
    gemm1_mfma<<<dim3(3072), 256, 0, stream>>>(
        item, pos, neg, W1bf, b1, gam, bet, rmu, rvr, h);
    gemm2_mfma<<<dim3(4096), 256, 0, stream>>>(
        h, W2bf, b2, pdp, pdn, pl2);
    margins_kernel<<<dim3(NROWS/256), 256, 0, stream>>>(pdp, pdn, margins, dd);
    final_kernel<<<1, 1024, 0, stream>>>(pl2, 4096, margins, dd, (float*)d_out);
}

// Round 5
// 501.936 us; speedup vs baseline: 1.1166x; 1.1166x over previous
//
#include <hip/hip_runtime.h>

#define NROWS 32768
#define DIM   1024
#define HIDD  512
#define M3    (3*NROWS)

using bf16x8 = __attribute__((ext_vector_type(8))) short;
using f32x4  = __attribute__((ext_vector_type(4))) float;

#define MFMA16(a,b,c) __builtin_amdgcn_mfma_f32_16x16x32_bf16(a,b,c,0,0,0)
#define WAIT_VM(N)  asm volatile("s_waitcnt vmcnt(" #N ")" ::: "memory")
#define WAIT_LGKM0  asm volatile("s_waitcnt lgkmcnt(0)" ::: "memory")
#define MEMFENCE    asm volatile("" ::: "memory")
#define BAR()       __builtin_amdgcn_s_barrier()
#define SCHEDB()    __builtin_amdgcn_sched_barrier(0)
#define SP1()       __builtin_amdgcn_s_setprio(1)
#define SP0()       __builtin_amdgcn_s_setprio(0)

// ---------- helpers ----------
static __device__ __forceinline__ unsigned short f2bf(float f) {
    unsigned u = __float_as_uint(f);
    u += 0x7FFFu + ((u >> 16) & 1u);   // round-to-nearest-even
    return (unsigned short)(u >> 16);
}
static __device__ __forceinline__ unsigned cvtpk(float a, float b) {
    unsigned r;
    asm("v_cvt_pk_bf16_f32 %0, %1, %2" : "=v"(r) : "v"(a), "v"(b));
    return r;
}
static __device__ __forceinline__ void gload16(const void* gsrc, void* ldst) {
    __builtin_amdgcn_global_load_lds(
        (const __attribute__((address_space(1))) unsigned int*)gsrc,
        (__attribute__((address_space(3))) unsigned int*)ldst,
        16, 0, 0);
}

// ---------- convert fp32 -> bf16 (for W1, W2) ----------
__global__ __launch_bounds__(256)
void cvt_kernel(const float* __restrict__ src, unsigned short* __restrict__ dst, int n4)
{
    const int i = blockIdx.x * 256 + threadIdx.x;
    if (i < n4) {
        float4 v = reinterpret_cast<const float4*>(src)[i];
        uint2 o;
        o.x = cvtpk(v.x, v.y);
        o.y = cvtpk(v.z, v.w);
        reinterpret_cast<uint2*>(dst)[i] = o;
    }
}

// ---------- GEMM1 (8-phase 256x256): h = leaky(bn(x @ W1^T + b1)), h bf16 [3N][512] ----------
// 768 blocks XCD-swizzled, 512 thr / 8 waves (2M x 4N), per-wave 128x64, BK=64, 16 K-tiles.
__global__ __launch_bounds__(512, 1)
void gemm1_mfma(const float* __restrict__ x0, const float* __restrict__ x1,
                const float* __restrict__ x2,
                const unsigned short* __restrict__ W1bf,
                const float* __restrict__ b1, const float* __restrict__ gamma,
                const float* __restrict__ beta, const float* __restrict__ rmean,
                const float* __restrict__ rvar,
                unsigned short* __restrict__ h)
{
    __shared__ char smem[131072];
    char* const Ab = smem;            // 2 x 32768: A[par][row 256][k 64] bf16, addr-XOR swz
    char* const Bb = smem + 65536;    // 2 x 32768: B[par][col 256][k 64] bf16, src-preswz

    const int lin = blockIdx.x;       // 768 = 8 XCD * 96
    const int wgid = (lin & 7) * 96 + (lin >> 3);
    const int cb = wgid & 1;
    const int rb = wgid >> 1;         // 0..383
    const int tid  = threadIdx.x;
    const int lane = tid & 63, w = tid >> 6;
    const int wm = w >> 2, wn = w & 3;
    const int row0 = rb * 256;
    const int s = row0 >> 15;
    const float* x = (s == 0) ? x0 : (s == 1 ? x1 : x2);
    const int rl0 = row0 & (NROWS - 1);
    const int col0 = cb * 256;
    const int l15 = lane & 15, lq = lane >> 4;

    f32x4 acc[8][4] = {};
    float4 aR[8];

    const int arow = tid >> 1, ahalf = tid & 1;
    const float* axsrc = &x[(size_t)(rl0 + arow) * DIM + ahalf * 32];

    auto issueA = [&](int k0) {
        #pragma unroll
        for (int j = 0; j < 8; ++j)
            aR[j] = *reinterpret_cast<const float4*>(axsrc + k0 + j * 4);
    };
    auto issueB = [&](int k0, char* Bdst) {
        #pragma unroll
        for (int i = 0; i < 4; ++i) {
            const int f = i * 512 + tid;
            const int col = f >> 3, c = f & 7;
            gload16(&W1bf[(size_t)(col0 + col) * DIM + k0 + ((c ^ (col & 7)) << 3)],
                    Bdst + f * 16);
        }
    };
    auto writeA = [&](char* Adst) {
        #pragma unroll
        for (int j = 0; j < 4; ++j) {
            uint4 o;
            o.x = cvtpk(aR[2*j].x, aR[2*j].y);
            o.y = cvtpk(aR[2*j].z, aR[2*j].w);
            o.z = cvtpk(aR[2*j+1].x, aR[2*j+1].y);
            o.w = cvtpk(aR[2*j+1].z, aR[2*j+1].w);
            const int cidx = ahalf * 4 + j;
            *reinterpret_cast<uint4*>(Adst + ((arow * 128 + cidx * 16) ^ ((arow & 7) << 4))) = o;
        }
    };
    auto readA = [&](bf16x8 (&a)[4][2], int mh, char* Abase) {
        #pragma unroll
        for (int mm = 0; mm < 4; ++mm) {
            const int row = wm * 128 + (mh * 4 + mm) * 16 + l15;
            const int swz = (row & 7) << 4;
            #pragma unroll
            for (int ks = 0; ks < 2; ++ks)
                a[mm][ks] = *reinterpret_cast<const bf16x8*>(
                    Abase + ((row * 128 + ks * 64 + lq * 16) ^ swz));
        }
    };
    auto readB = [&](bf16x8 (&b)[2][2], int nh, char* Bbase) {
        #pragma unroll
        for (int nn = 0; nn < 2; ++nn) {
            const int col = wn * 64 + (nh * 2 + nn) * 16 + l15;
            const int swz = (col & 7) << 4;
            #pragma unroll
            for (int ks = 0; ks < 2; ++ks)
                b[nn][ks] = *reinterpret_cast<const bf16x8*>(
                    Bbase + ((col * 128 + ks * 64 + lq * 16) ^ swz));
        }
    };

    // ---- prologue: stage tile 0 ----
    issueA(0);
    MEMFENCE;
    issueB(0, Bb);
    WAIT_VM(4);             // A(0) f4s done (B(0) still in flight)
    writeA(Ab);
    WAIT_VM(0);             // B(0) landed
    WAIT_LGKM0;
    BAR();

    for (int t = 0; t < 16; ++t) {
        char* const Apt = Ab + (t & 1) * 32768;
        char* const Apn = Ab + ((t & 1) ^ 1) * 32768;
        char* const Bpt = Bb + (t & 1) * 32768;
        char* const Bpn = Bb + ((t & 1) ^ 1) * 32768;
        const int kn = ((t < 15) ? (t + 1) : 15) * 64;

        bf16x8 a[4][2], b[2][2], a2[4][2];
        // ---- P1: quadrant (0,0); issue A(t+1) f4 + B(t+1) gload ----
        readA(a, 0, Apt);
        readB(b, 0, Bpt);
        issueA(kn);
        MEMFENCE;
        issueB(kn, Bpn);
        BAR(); WAIT_LGKM0; SCHEDB(); SP1();
        #pragma unroll
        for (int mm = 0; mm < 4; ++mm)
            #pragma unroll
            for (int nn = 0; nn < 2; ++nn)
                #pragma unroll
                for (int ks = 0; ks < 2; ++ks)
                    acc[mm][nn] = MFMA16(a[mm][ks], b[nn][ks], acc[mm][nn]);
        SP0(); BAR();
        // ---- P2: quadrant (0,1) ----
        readB(b, 1, Bpt);
        BAR(); WAIT_LGKM0; SCHEDB(); SP1();
        #pragma unroll
        for (int mm = 0; mm < 4; ++mm)
            #pragma unroll
            for (int nn = 0; nn < 2; ++nn)
                #pragma unroll
                for (int ks = 0; ks < 2; ++ks)
                    acc[mm][2 + nn] = MFMA16(a[mm][ks], b[nn][ks], acc[mm][2 + nn]);
        SP0(); BAR();
        // ---- P3: quadrant (1,1); drain A(t+1), ds_write it ----
        readA(a2, 1, Apt);
        WAIT_VM(4);
        writeA(Apn);
        BAR(); WAIT_LGKM0; SCHEDB(); SP1();
        #pragma unroll
        for (int mm = 0; mm < 4; ++mm)
            #pragma unroll
            for (int nn = 0; nn < 2; ++nn)
                #pragma unroll
                for (int ks = 0; ks < 2; ++ks)
                    acc[4 + mm][2 + nn] = MFMA16(a2[mm][ks], b[nn][ks], acc[4 + mm][2 + nn]);
        SP0(); BAR();
        // ---- P4: quadrant (1,0); drain B(t+1) ----
        readB(b, 0, Bpt);
        WAIT_VM(0);
        BAR(); WAIT_LGKM0; SCHEDB(); SP1();
        #pragma unroll
        for (int mm = 0; mm < 4; ++mm)
            #pragma unroll
            for (int nn = 0; nn < 2; ++nn)
                #pragma unroll
                for (int ks = 0; ks < 2; ++ks)
                    acc[4 + mm][nn] = MFMA16(a2[mm][ks], b[nn][ks], acc[4 + mm][nn]);
        SP0(); BAR();
    }

    // epilogue: BN(eval) + leaky folded to v*A + B per column
    float Asc[4], Bsc[4];
    #pragma unroll
    for (int nf = 0; nf < 4; ++nf) {
        const int c = col0 + wn * 64 + nf * 16 + l15;
        const float inv = rsqrtf(rvar[c] + 1e-5f);
        Asc[nf] = inv * gamma[c];
        Bsc[nf] = (b1[c] - rmean[c]) * Asc[nf] + beta[c];
    }
    #pragma unroll
    for (int mf = 0; mf < 8; ++mf) {
        const int rbase = row0 + wm * 128 + mf * 16 + lq * 4;
        #pragma unroll
        for (int nf = 0; nf < 4; ++nf) {
            const int c = col0 + wn * 64 + nf * 16 + l15;
            #pragma unroll
            for (int i = 0; i < 4; ++i) {
                float v = fmaf(acc[mf][nf][i], Asc[nf], Bsc[nf]);
                v = (v >= 0.f) ? v : 0.1f * v;
                h[(size_t)(rbase + i) * HIDD + c] = f2bf(v);
            }
        }
    }
}

// ---------- GEMM2 (8-phase fused): e = h @ W2^T + b2 for a/p/n; distances + L2 ----------
// 2048 blocks XCD-swizzled, 512 thr / 8 waves (2M x 4N). Tile: M=192 (64 rows x 3 streams,
// stream = m-frag % 3), N=256, BK=64, 8 K-tiles. Pure gload16 staging.
__global__ __launch_bounds__(512, 1)
void gemm2_mfma(const unsigned short* __restrict__ h,
                const unsigned short* __restrict__ W2bf,
                const float* __restrict__ b2,
                float* __restrict__ pdp, float* __restrict__ pdn,
                float* __restrict__ pl2)
{
    __shared__ char smem[114688];
    char* const Ab = smem;            // 2 x 24576: A[par][mrow 192][k 64]
    char* const Bb = smem + 49152;    // 2 x 32768: B[par][col 256][k 64]

    const int lin = blockIdx.x;       // 2048 = 8 XCD * 256
    const int wgid = (lin & 7) * 256 + (lin >> 3);
    const int cb = wgid & 3;
    const int rb = wgid >> 2;         // 0..511
    const int tid  = threadIdx.x;
    const int lane = tid & 63, w = tid >> 6;
    const int wm = w >> 2, wn = w & 3;
    const int row0 = rb * 64;
    const int col0 = cb * 256;
    const int l15 = lane & 15, lq = lane >> 4;

    f32x4 acc[6][4] = {};             // [mh*3 + stream][nf]

    auto issueA = [&](int k0, char* Adst) {
        #pragma unroll
        for (int i = 0; i < 3; ++i) {
            const int f = i * 512 + tid;       // 0..1535
            const int mrow = f >> 3, c = f & 7;
            const int mf = mrow >> 4, rr = mrow & 15;
            const int ss = mf % 3, rf = mf / 3;
            gload16(&h[((size_t)ss * NROWS + row0 + rf * 16 + rr) * HIDD + k0 + ((c ^ (mrow & 7)) << 3)],
                    Adst + f * 16);
        }
    };
    auto issueB = [&](int k0, char* Bdst) {
        #pragma unroll
        for (int i = 0; i < 4; ++i) {
            const int f = i * 512 + tid;
            const int col = f >> 3, c = f & 7;
            gload16(&W2bf[(size_t)(col0 + col) * HIDD + k0 + ((c ^ (col & 7)) << 3)],
                    Bdst + f * 16);
        }
    };
    auto readA = [&](bf16x8 (&a)[3][2], int mh, char* Abase) {
        #pragma unroll
        for (int mm = 0; mm < 3; ++mm) {
            const int row = (wm * 6 + mh * 3 + mm) * 16 + l15;
            const int swz = (row & 7) << 4;
            #pragma unroll
            for (int ks = 0; ks < 2; ++ks)
                a[mm][ks] = *reinterpret_cast<const bf16x8*>(
                    Abase + ((row * 128 + ks * 64 + lq * 16) ^ swz));
        }
    };
    auto readB = [&](bf16x8 (&b)[2][2], int nh, char* Bbase) {
        #pragma unroll
        for (int nn = 0; nn < 2; ++nn) {
            const int col = wn * 64 + (nh * 2 + nn) * 16 + l15;
            const int swz = (col & 7) << 4;
            #pragma unroll
            for (int ks = 0; ks < 2; ++ks)
                b[nn][ks] = *reinterpret_cast<const bf16x8*>(
                    Bbase + ((col * 128 + ks * 64 + lq * 16) ^ swz));
        }
    };

    // ---- prologue ----
    issueA(0, Ab);
    MEMFENCE;
    issueB(0, Bb);
    WAIT_VM(0);
    BAR();

    for (int t = 0; t < 8; ++t) {
        char* const Apt = Ab + (t & 1) * 24576;
        char* const Apn = Ab + ((t & 1) ^ 1) * 24576;
        char* const Bpt = Bb + (t & 1) * 32768;
        char* const Bpn = Bb + ((t & 1) ^ 1) * 32768;
        const int kn = ((t < 7) ? (t + 1) : 7) * 64;

        bf16x8 a[3][2], b[2][2], a2[3][2];
        // ---- P1: (0,0); issue A(t+1)+B(t+1) ----
        readA(a, 0, Apt);
        readB(b, 0, Bpt);
        issueA(kn, Apn);
        MEMFENCE;
        issueB(kn, Bpn);
        BAR(); WAIT_LGKM0; SCHEDB(); SP1();
        #pragma unroll
        for (int mm = 0; mm < 3; ++mm)
            #pragma unroll
            for (int nn = 0; nn < 2; ++nn)
                #pragma unroll
                for (int ks = 0; ks < 2; ++ks)
                    acc[mm][nn] = MFMA16(a[mm][ks], b[nn][ks], acc[mm][nn]);
        SP0(); BAR();
        // ---- P2: (0,1) ----
        readB(b, 1, Bpt);
        BAR(); WAIT_LGKM0; SCHEDB(); SP1();
        #pragma unroll
        for (int mm = 0; mm < 3; ++mm)
            #pragma unroll
            for (int nn = 0; nn < 2; ++nn)
                #pragma unroll
                for (int ks = 0; ks < 2; ++ks)
                    acc[mm][2 + nn] = MFMA16(a[mm][ks], b[nn][ks], acc[mm][2 + nn]);
        SP0(); BAR();
        // ---- P3: (1,1) ----
        readA(a2, 1, Apt);
        BAR(); WAIT_LGKM0; SCHEDB(); SP1();
        #pragma unroll
        for (int mm = 0; mm < 3; ++mm)
            #pragma unroll
            for (int nn = 0; nn < 2; ++nn)
                #pragma unroll
                for (int ks = 0; ks < 2; ++ks)
                    acc[3 + mm][2 + nn] = MFMA16(a2[mm][ks], b[nn][ks], acc[3 + mm][2 + nn]);
        SP0(); BAR();
        // ---- P4: (1,0); drain prefetches (3 phases of cover) ----
        readB(b, 0, Bpt);
        WAIT_VM(0);
        BAR(); WAIT_LGKM0; SCHEDB(); SP1();
        #pragma unroll
        for (int mm = 0; mm < 3; ++mm)
            #pragma unroll
            for (int nn = 0; nn < 2; ++nn)
                #pragma unroll
                for (int ks = 0; ks < 2; ++ks)
                    acc[3 + mm][nn] = MFMA16(a2[mm][ks], b[nn][ks], acc[3 + mm][nn]);
        SP0(); BAR();
    }

    // epilogue: distances + L2 (stream = acc row % 3), never materializing e
    float b2c[4];
    #pragma unroll
    for (int nf = 0; nf < 4; ++nf) b2c[nf] = b2[col0 + wn * 64 + nf * 16 + l15];
    float l2t = 0.f;
    #pragma unroll
    for (int mh = 0; mh < 2; ++mh) {
        const int rbase = row0 + (wm * 2 + mh) * 16 + lq * 4;
        #pragma unroll
        for (int i = 0; i < 4; ++i) {
            float dp = 0.f, dn = 0.f;
            #pragma unroll
            for (int nf = 0; nf < 4; ++nf) {
                const float ea = acc[mh * 3 + 0][nf][i] + b2c[nf];
                const float ep = acc[mh * 3 + 1][nf][i] + b2c[nf];
                const float en = acc[mh * 3 + 2][nf][i] + b2c[nf];
                dp += (ea - ep) * (ea - ep);
                dn += (ea - en) * (ea - en);
                l2t += ea * ea + ep * ep + en * en;
            }
            #pragma unroll
            for (int mm = 1; mm < 16; mm <<= 1) {
                dp += __shfl_xor(dp, mm);
                dn += __shfl_xor(dn, mm);
            }
            if (l15 == 0) {
                pdp[(size_t)(cb * 4 + wn) * NROWS + rbase + i] = dp;
                pdn[(size_t)(cb * 4 + wn) * NROWS + rbase + i] = dn;
            }
        }
    }
    #pragma unroll
    for (int mm = 1; mm < 64; mm <<= 1) l2t += __shfl_xor(l2t, mm);
    __syncthreads();
    float* const l2red = (float*)smem;
    if (lane == 0) l2red[w] = l2t;
    __syncthreads();
    if (tid == 0) {
        float t = 0.f;
        #pragma unroll
        for (int ww = 0; ww < 8; ++ww) t += l2red[ww];
        pl2[wgid] = t;
    }
}

// ---------- per-row margins ----------
__global__ __launch_bounds__(256)
void margins_kernel(const float* __restrict__ pdp, const float* __restrict__ pdn,
                    float* __restrict__ margins, float* __restrict__ dd)
{
    const int r = blockIdx.x * 256 + threadIdx.x;
    float dp2 = 0.f, dn2 = 0.f;
    #pragma unroll
    for (int q = 0; q < 16; ++q) {
        dp2 += pdp[(size_t)q * NROWS + r];
        dn2 += pdn[(size_t)q * NROWS + r];
    }
    dd[r] = dn2 - dp2;
    margins[r] = (dn2 < dp2) ? (sqrtf(dp2) - sqrtf(dn2)) : 0.f;
}

// ---------- final: l2 sum + radix-select quantile + loss ----------
__global__ __launch_bounds__(1024)
void final_kernel(const float* __restrict__ pl2, int npl2,
                  const float* __restrict__ margins, const float* __restrict__ dd,
                  float* __restrict__ out)
{
    __shared__ unsigned hist[256];
    __shared__ float warp_red[16];
    __shared__ unsigned sh_prefix;
    __shared__ int sh_k;
    __shared__ float sh_l2;
    const int tid = threadIdx.x;

    float l2 = 0.f;
    for (int i = tid; i < npl2; i += 1024) l2 += pl2[i];
    #pragma unroll
    for (int m = 1; m < 64; m <<= 1) l2 += __shfl_xor(l2, m);
    if ((tid & 63) == 0) warp_red[tid >> 6] = l2;
    __syncthreads();
    if (tid == 0) {
        float t = 0.f;
        for (int w = 0; w < 16; ++w) t += warp_red[w];
        sh_l2 = t;
    }
    __syncthreads();

    float vsel[2];
    for (int sel = 0; sel < 2; ++sel) {
        if (tid == 0) { sh_k = 8191 + sel; sh_prefix = 0u; }
        __syncthreads();
        for (int shift = 24; shift >= 0; shift -= 8) {
            if (tid < 256) hist[tid] = 0u;
            __syncthreads();
            const unsigned prefix = sh_prefix;
            const unsigned mask = (shift == 24) ? 0u : (0xFFFFFFFFu << (shift + 8));
            for (int i = tid; i < NROWS; i += 1024) {
                const unsigned key = __float_as_uint(margins[i]);
                if (((key ^ prefix) & mask) == 0u)
                    atomicAdd(&hist[(key >> shift) & 255u], 1u);
            }
            __syncthreads();
            if (tid == 0) {
                int kk = sh_k;
                unsigned cum = 0; int d = 0;
                for (; d < 256; ++d) {
                    const unsigned c = hist[d];
                    if (cum + c > (unsigned)kk) break;
                    cum += c;
                }
                sh_prefix = prefix | ((unsigned)d << shift);
                sh_k = kk - (int)cum;
            }
            __syncthreads();
        }
        vsel[sel] = __uint_as_float(sh_prefix);
        __syncthreads();
    }
    const float margin = vsel[0] + 0.75f * (vsel[1] - vsel[0]);

    float ssum = 0.f;
    for (int i = tid; i < NROWS; i += 1024) {
        const float t = dd[i] + margin;
        ssum += (t > 0.f) ? t : 0.f;
    }
    #pragma unroll
    for (int m = 1; m < 64; m <<= 1) ssum += __shfl_xor(ssum, m);
    if ((tid & 63) == 0) warp_red[tid >> 6] = ssum;
    __syncthreads();
    if (tid == 0) {
        float S = 0.f;
        for (int w = 0; w < 16; ++w) S += warp_red[w];
        out[0] = S / (float)NROWS + 1e-3f * sh_l2 / (float)NROWS;
    }
}

extern "C" void kernel_launch(void* const* d_in, const int* in_sizes, int n_in,
                              void* d_out, int out_size, void* d_ws, size_t ws_size,
                              hipStream_t stream) {
    (void)in_sizes; (void)n_in; (void)out_size; (void)ws_size;
    const float* item = (const float*)d_in[0];
    const float* pos  = (const float*)d_in[1];
    const float* neg  = (const float*)d_in[2];
    const float* W1   = (const float*)d_in[3];
    const float* b1   = (const float*)d_in[4];
    const float* gam  = (const float*)d_in[5];
    const float* bet  = (const float*)d_in[6];
    const float* rmu  = (const float*)d_in[7];
    const float* rvr  = (const float*)d_in[8];
    const float* W2   = (const float*)d_in[9];
    const float* b2   = (const float*)d_in[10];

    char* ws = (char*)d_ws;
    unsigned short* h = (unsigned short*)ws;
    size_t off = (size_t)M3 * HIDD * sizeof(unsigned short);
    unsigned short* W1bf = (unsigned short*)(ws + off); off += (size_t)HIDD * DIM * 2;
    unsigned short* W2bf = (unsigned short*)(ws + off); off += (size_t)DIM * HIDD * 2;
    float* pdp = (float*)(ws + off); off += (size_t)16 * NROWS * 4;
    float* pdn = (float*)(ws + off); off += (size_t)16 * NROWS * 4;
    float* pl2 = (float*)(ws + off); off += (size_t)2048 * 4;
    float* margins = (float*)(ws + off); off += (size_t)NROWS * 4;
    float* dd = (float*)(ws + off); off += (size_t)NROWS * 4;

    cvt_kernel<<<dim3((HIDD*DIM/4 + 255)/256), 256, 0, stream>>>(W1, W1bf, HIDD*DIM/4);
    cvt_kernel<<<dim3((DIM*HIDD/4 + 255)/256), 256, 0, stream>>>(W2, W2bf, DIM*HIDD/4);
    gemm1_mfma<<<dim3(768), 512, 0, stream>>>(
        item, pos, neg, W1bf, b1, gam, bet, rmu, rvr, h);
    gemm2_mfma<<<dim3(2048), 512, 0, stream>>>(
        h, W2bf, b2, pdp, pdn, pl2);
    margins_kernel<<<dim3(NROWS/256), 256, 0, stream>>>(pdp, pdn, margins, dd);
    final_kernel<<<1, 1024, 0, stream>>>(pl2, 2048, margins, dd, (float*)d_out);
}

// Round 6
// 438.937 us; speedup vs baseline: 1.2769x; 1.1435x over previous
//
#include <hip/hip_runtime.h>

#define NROWS 32768
#define DIM   1024
#define HIDD  512
#define M3    (3*NROWS)

using bf16x8 = __attribute__((ext_vector_type(8))) short;
using f32x4  = __attribute__((ext_vector_type(4))) float;

#define MFMA16(a,b,c) __builtin_amdgcn_mfma_f32_16x16x32_bf16(a,b,c,0,0,0)
#define WAIT_VM(N)  asm volatile("s_waitcnt vmcnt(" #N ")" ::: "memory")
#define WAIT_LGKM0  asm volatile("s_waitcnt lgkmcnt(0)" ::: "memory")
#define MEMFENCE    asm volatile("" ::: "memory")
#define BAR()       __builtin_amdgcn_s_barrier()
#define SCHEDB()    __builtin_amdgcn_sched_barrier(0)
#define SP1()       __builtin_amdgcn_s_setprio(1)
#define SP0()       __builtin_amdgcn_s_setprio(0)

// ---------- helpers ----------
static __device__ __forceinline__ unsigned cvtpk(float a, float b) {
    unsigned r;
    asm("v_cvt_pk_bf16_f32 %0, %1, %2" : "=v"(r) : "v"(a), "v"(b));
    return r;
}
static __device__ __forceinline__ void gload16(const void* gsrc, void* ldst) {
    __builtin_amdgcn_global_load_lds(
        (const __attribute__((address_space(1))) unsigned int*)gsrc,
        (__attribute__((address_space(3))) unsigned int*)ldst,
        16, 0, 0);
}

// ---------- convert fp32 -> bf16 (for W1, W2) ----------
__global__ __launch_bounds__(256)
void cvt_kernel(const float* __restrict__ src, unsigned short* __restrict__ dst, int n4)
{
    const int i = blockIdx.x * 256 + threadIdx.x;
    if (i < n4) {
        float4 v = reinterpret_cast<const float4*>(src)[i];
        uint2 o;
        o.x = cvtpk(v.x, v.y);
        o.y = cvtpk(v.z, v.w);
        reinterpret_cast<uint2*>(dst)[i] = o;
    }
}

// ---------- GEMM1 (swapped-operand MFMA): h = leaky(bn(x @ W1^T + b1)), h bf16 [3N][512] ----------
// 3072 blocks XCD-swizzled. Tile r128 x c128, BK=64, 4 waves each own r64 x c64 (4x4 frags).
// D = A(W1) x B(x^T): lane col = batch row r, acc rows = h-col c -> lane holds 4 consecutive
// h columns per acc quad -> cvtpk + 8B stores (4x fewer store instrs than scalar bf16).
__global__ __launch_bounds__(256)
void gemm1_mfma(const float* __restrict__ x0, const float* __restrict__ x1,
                const float* __restrict__ x2,
                const unsigned short* __restrict__ W1bf,
                const float* __restrict__ b1, const float* __restrict__ gamma,
                const float* __restrict__ beta, const float* __restrict__ rmean,
                const float* __restrict__ rvar,
                unsigned short* __restrict__ h)
{
    __shared__ char smem[32768];
    char* const Xb = smem;            // [128 r][64 k] bf16, byte ^((r&7)<<4)
    char* const Wb = smem + 16384;    // [2 panel][128 c][32 k] bf16, src chunk-permuted

    const int lin = blockIdx.x;       // 3072 = 8 XCD * 384
    const int wgid = (lin & 7) * 384 + (lin >> 3);
    const int cb = wgid & 3;
    const int rb = wgid >> 2;
    const int tid  = threadIdx.x;
    const int lane = tid & 63, w = tid >> 6;
    const int wr = w >> 1, wc = w & 1;
    const int row0 = rb * 128;
    const int s = row0 >> 15;
    const float* x = (s == 0) ? x0 : (s == 1 ? x1 : x2);
    const int rl0 = row0 & (NROWS - 1);
    const int col0 = cb * 128;
    const int l15 = lane & 15, lq = lane >> 4;

    f32x4 acc[4][4] = {};             // [cf][rf]
    float4 aR[8];

    // prefetch x tile 0 into regs
    #pragma unroll
    for (int p = 0; p < 8; ++p) {
        const int f = p * 256 + tid;  // 0..2047
        const int r = f >> 4, c4 = f & 15;
        aR[p] = *reinterpret_cast<const float4*>(&x[(size_t)(rl0 + r) * DIM + c4 * 4]);
    }

    for (int t = 0; t < 16; ++t) {
        const int k0 = t * 64;
        // ---- stage x (cvt from regs, XOR-swizzled) ----
        #pragma unroll
        for (int p = 0; p < 8; ++p) {
            const int f = p * 256 + tid;
            const int r = f >> 4, c4 = f & 15;
            const unsigned off = (unsigned)((r * 128 + c4 * 8) ^ ((r & 7) << 4));
            uint2 o; o.x = cvtpk(aR[p].x, aR[p].y); o.y = cvtpk(aR[p].z, aR[p].w);
            *reinterpret_cast<uint2*>(Xb + off) = o;
        }
        // ---- stage W1 via global_load_lds (source chunk-permuted) ----
        #pragma unroll
        for (int c = 0; c < 4; ++c) {
            const int f = c * 256 + tid;        // 0..1023
            const int panel = f >> 9;
            const int cc = (f >> 2) & 127;
            const int chunk = (f & 3) ^ ((cc >> 1) & 3);
            gload16(&W1bf[(size_t)(col0 + cc) * DIM + k0 + panel * 32 + chunk * 8],
                    Wb + (size_t)f * 16);
        }
        __syncthreads();
        // ---- issue next x loads (drain hidden under MFMA at next barrier) ----
        if (t < 15) {
            #pragma unroll
            for (int p = 0; p < 8; ++p) {
                const int f = p * 256 + tid;
                const int r = f >> 4, c4 = f & 15;
                aR[p] = *reinterpret_cast<const float4*>(
                    &x[(size_t)(rl0 + r) * DIM + k0 + 64 + c4 * 4]);
            }
        }
        // ---- fragments + MFMA (A = W1 frag, B = x frag) ----
        bf16x8 wf[2][4], xf[2][4];
        #pragma unroll
        for (int kk = 0; kk < 2; ++kk) {
            #pragma unroll
            for (int cf = 0; cf < 4; ++cf) {
                const int colr = wc * 64 + cf * 16 + l15;
                const int slq = lq ^ ((colr >> 1) & 3);
                wf[kk][cf] = *reinterpret_cast<const bf16x8*>(Wb + kk * 8192 + colr * 64 + slq * 16);
            }
            #pragma unroll
            for (int rf = 0; rf < 4; ++rf) {
                const int row = wr * 64 + rf * 16 + l15;
                xf[kk][rf] = *reinterpret_cast<const bf16x8*>(
                    Xb + ((row * 128 + kk * 64 + lq * 16) ^ ((row & 7) << 4)));
            }
        }
        #pragma unroll
        for (int kk = 0; kk < 2; ++kk)
            #pragma unroll
            for (int cf = 0; cf < 4; ++cf)
                #pragma unroll
                for (int rf = 0; rf < 4; ++rf)
                    acc[cf][rf] = MFMA16(wf[kk][cf], xf[kk][rf], acc[cf][rf]);
        __syncthreads();
    }

    // ---- BN params per column into LDS ----
    float2* const sAB = (float2*)smem;            // [128] (scale, bias)
    if (tid < 128) {
        const int c = col0 + tid;
        const float a = rsqrtf(rvar[c] + 1e-5f) * gamma[c];
        sAB[tid] = make_float2(a, (b1[c] - rmean[c]) * a + beta[c]);
    }
    __syncthreads();

    // ---- epilogue: BN + leaky + pack 4 consecutive cols -> 8B store ----
    #pragma unroll
    for (int cf = 0; cf < 4; ++cf) {
        const int cbase = wc * 64 + cf * 16 + lq * 4;
        const float2 ab0 = sAB[cbase + 0];
        const float2 ab1 = sAB[cbase + 1];
        const float2 ab2 = sAB[cbase + 2];
        const float2 ab3 = sAB[cbase + 3];
        #pragma unroll
        for (int rf = 0; rf < 4; ++rf) {
            const int r = row0 + wr * 64 + rf * 16 + l15;
            float v0 = fmaf(acc[cf][rf][0], ab0.x, ab0.y);
            float v1 = fmaf(acc[cf][rf][1], ab1.x, ab1.y);
            float v2 = fmaf(acc[cf][rf][2], ab2.x, ab2.y);
            float v3 = fmaf(acc[cf][rf][3], ab3.x, ab3.y);
            v0 = (v0 >= 0.f) ? v0 : 0.1f * v0;
            v1 = (v1 >= 0.f) ? v1 : 0.1f * v1;
            v2 = (v2 >= 0.f) ? v2 : 0.1f * v2;
            v3 = (v3 >= 0.f) ? v3 : 0.1f * v3;
            uint2 o; o.x = cvtpk(v0, v1); o.y = cvtpk(v2, v3);
            *reinterpret_cast<uint2*>(&h[(size_t)r * HIDD + col0 + cbase]) = o;
        }
    }
}

// ---------- GEMM2 (8-phase fused): e = h @ W2^T + b2 for a/p/n; distances + L2 ----------
// 2048 blocks XCD-swizzled, 512 thr / 8 waves (2M x 4N). Tile: M=192 (64 rows x 3 streams,
// stream = m-frag % 3), N=256, BK=64, 8 K-tiles. Pure gload16 staging. (unchanged from R5)
__global__ __launch_bounds__(512, 1)
void gemm2_mfma(const unsigned short* __restrict__ h,
                const unsigned short* __restrict__ W2bf,
                const float* __restrict__ b2,
                float* __restrict__ pdp, float* __restrict__ pdn,
                float* __restrict__ pl2)
{
    __shared__ char smem[114688];
    char* const Ab = smem;            // 2 x 24576: A[par][mrow 192][k 64]
    char* const Bb = smem + 49152;    // 2 x 32768: B[par][col 256][k 64]

    const int lin = blockIdx.x;       // 2048 = 8 XCD * 256
    const int wgid = (lin & 7) * 256 + (lin >> 3);
    const int cb = wgid & 3;
    const int rb = wgid >> 2;         // 0..511
    const int tid  = threadIdx.x;
    const int lane = tid & 63, w = tid >> 6;
    const int wm = w >> 2, wn = w & 3;
    const int row0 = rb * 64;
    const int col0 = cb * 256;
    const int l15 = lane & 15, lq = lane >> 4;

    f32x4 acc[6][4] = {};             // [mh*3 + stream][nf]

    auto issueA = [&](int k0, char* Adst) {
        #pragma unroll
        for (int i = 0; i < 3; ++i) {
            const int f = i * 512 + tid;       // 0..1535
            const int mrow = f >> 3, c = f & 7;
            const int mf = mrow >> 4, rr = mrow & 15;
            const int ss = mf % 3, rf = mf / 3;
            gload16(&h[((size_t)ss * NROWS + row0 + rf * 16 + rr) * HIDD + k0 + ((c ^ (mrow & 7)) << 3)],
                    Adst + f * 16);
        }
    };
    auto issueB = [&](int k0, char* Bdst) {
        #pragma unroll
        for (int i = 0; i < 4; ++i) {
            const int f = i * 512 + tid;
            const int col = f >> 3, c = f & 7;
            gload16(&W2bf[(size_t)(col0 + col) * HIDD + k0 + ((c ^ (col & 7)) << 3)],
                    Bdst + f * 16);
        }
    };
    auto readA = [&](bf16x8 (&a)[3][2], int mh, char* Abase) {
        #pragma unroll
        for (int mm = 0; mm < 3; ++mm) {
            const int row = (wm * 6 + mh * 3 + mm) * 16 + l15;
            const int swz = (row & 7) << 4;
            #pragma unroll
            for (int ks = 0; ks < 2; ++ks)
                a[mm][ks] = *reinterpret_cast<const bf16x8*>(
                    Abase + ((row * 128 + ks * 64 + lq * 16) ^ swz));
        }
    };
    auto readB = [&](bf16x8 (&b)[2][2], int nh, char* Bbase) {
        #pragma unroll
        for (int nn = 0; nn < 2; ++nn) {
            const int col = wn * 64 + (nh * 2 + nn) * 16 + l15;
            const int swz = (col & 7) << 4;
            #pragma unroll
            for (int ks = 0; ks < 2; ++ks)
                b[nn][ks] = *reinterpret_cast<const bf16x8*>(
                    Bbase + ((col * 128 + ks * 64 + lq * 16) ^ swz));
        }
    };

    // ---- prologue ----
    issueA(0, Ab);
    MEMFENCE;
    issueB(0, Bb);
    WAIT_VM(0);
    BAR();

    for (int t = 0; t < 8; ++t) {
        char* const Apt = Ab + (t & 1) * 24576;
        char* const Apn = Ab + ((t & 1) ^ 1) * 24576;
        char* const Bpt = Bb + (t & 1) * 32768;
        char* const Bpn = Bb + ((t & 1) ^ 1) * 32768;
        const int kn = ((t < 7) ? (t + 1) : 7) * 64;

        bf16x8 a[3][2], b[2][2], a2[3][2];
        // ---- P1: (0,0); issue A(t+1)+B(t+1) ----
        readA(a, 0, Apt);
        readB(b, 0, Bpt);
        issueA(kn, Apn);
        MEMFENCE;
        issueB(kn, Bpn);
        BAR(); WAIT_LGKM0; SCHEDB(); SP1();
        #pragma unroll
        for (int mm = 0; mm < 3; ++mm)
            #pragma unroll
            for (int nn = 0; nn < 2; ++nn)
                #pragma unroll
                for (int ks = 0; ks < 2; ++ks)
                    acc[mm][nn] = MFMA16(a[mm][ks], b[nn][ks], acc[mm][nn]);
        SP0(); BAR();
        // ---- P2: (0,1) ----
        readB(b, 1, Bpt);
        BAR(); WAIT_LGKM0; SCHEDB(); SP1();
        #pragma unroll
        for (int mm = 0; mm < 3; ++mm)
            #pragma unroll
            for (int nn = 0; nn < 2; ++nn)
                #pragma unroll
                for (int ks = 0; ks < 2; ++ks)
                    acc[mm][2 + nn] = MFMA16(a[mm][ks], b[nn][ks], acc[mm][2 + nn]);
        SP0(); BAR();
        // ---- P3: (1,1) ----
        readA(a2, 1, Apt);
        BAR(); WAIT_LGKM0; SCHEDB(); SP1();
        #pragma unroll
        for (int mm = 0; mm < 3; ++mm)
            #pragma unroll
            for (int nn = 0; nn < 2; ++nn)
                #pragma unroll
                for (int ks = 0; ks < 2; ++ks)
                    acc[3 + mm][2 + nn] = MFMA16(a2[mm][ks], b[nn][ks], acc[3 + mm][2 + nn]);
        SP0(); BAR();
        // ---- P4: (1,0); drain prefetches (3 phases of cover) ----
        readB(b, 0, Bpt);
        WAIT_VM(0);
        BAR(); WAIT_LGKM0; SCHEDB(); SP1();
        #pragma unroll
        for (int mm = 0; mm < 3; ++mm)
            #pragma unroll
            for (int nn = 0; nn < 2; ++nn)
                #pragma unroll
                for (int ks = 0; ks < 2; ++ks)
                    acc[3 + mm][nn] = MFMA16(a2[mm][ks], b[nn][ks], acc[3 + mm][nn]);
        SP0(); BAR();
    }

    // epilogue: distances + L2 (stream = acc row % 3), never materializing e
    float b2c[4];
    #pragma unroll
    for (int nf = 0; nf < 4; ++nf) b2c[nf] = b2[col0 + wn * 64 + nf * 16 + l15];
    float l2t = 0.f;
    #pragma unroll
    for (int mh = 0; mh < 2; ++mh) {
        const int rbase = row0 + (wm * 2 + mh) * 16 + lq * 4;
        #pragma unroll
        for (int i = 0; i < 4; ++i) {
            float dp = 0.f, dn = 0.f;
            #pragma unroll
            for (int nf = 0; nf < 4; ++nf) {
                const float ea = acc[mh * 3 + 0][nf][i] + b2c[nf];
                const float ep = acc[mh * 3 + 1][nf][i] + b2c[nf];
                const float en = acc[mh * 3 + 2][nf][i] + b2c[nf];
                dp += (ea - ep) * (ea - ep);
                dn += (ea - en) * (ea - en);
                l2t += ea * ea + ep * ep + en * en;
            }
            #pragma unroll
            for (int mm = 1; mm < 16; mm <<= 1) {
                dp += __shfl_xor(dp, mm);
                dn += __shfl_xor(dn, mm);
            }
            if (l15 == 0) {
                pdp[(size_t)(cb * 4 + wn) * NROWS + rbase + i] = dp;
                pdn[(size_t)(cb * 4 + wn) * NROWS + rbase + i] = dn;
            }
        }
    }
    #pragma unroll
    for (int mm = 1; mm < 64; mm <<= 1) l2t += __shfl_xor(l2t, mm);
    __syncthreads();
    float* const l2red = (float*)smem;
    if (lane == 0) l2red[w] = l2t;
    __syncthreads();
    if (tid == 0) {
        float t = 0.f;
        #pragma unroll
        for (int ww = 0; ww < 8; ++ww) t += l2red[ww];
        pl2[wgid] = t;
    }
}

// ---------- per-row margins ----------
__global__ __launch_bounds__(256)
void margins_kernel(const float* __restrict__ pdp, const float* __restrict__ pdn,
                    float* __restrict__ margins, float* __restrict__ dd)
{
    const int r = blockIdx.x * 256 + threadIdx.x;
    float dp2 = 0.f, dn2 = 0.f;
    #pragma unroll
    for (int q = 0; q < 16; ++q) {
        dp2 += pdp[(size_t)q * NROWS + r];
        dn2 += pdn[(size_t)q * NROWS + r];
    }
    dd[r] = dn2 - dp2;
    margins[r] = (dn2 < dp2) ? (sqrtf(dp2) - sqrtf(dn2)) : 0.f;
}

// ---------- final: l2 sum + radix-select rank 8191 + neighbor pass + loss ----------
__global__ __launch_bounds__(1024)
void final_kernel(const float* __restrict__ pl2, int npl2,
                  const float* __restrict__ margins, const float* __restrict__ dd,
                  float* __restrict__ out)
{
    __shared__ unsigned hist[256];
    __shared__ float warp_red[16];
    __shared__ unsigned sh_prefix;
    __shared__ int sh_k;
    __shared__ float sh_l2;
    __shared__ unsigned sh_cle;
    __shared__ unsigned sh_minAbove;
    const int tid = threadIdx.x;

    // --- l2 sum over partials ---
    float l2 = 0.f;
    for (int i = tid; i < npl2; i += 1024) l2 += pl2[i];
    #pragma unroll
    for (int m = 1; m < 64; m <<= 1) l2 += __shfl_xor(l2, m);
    if ((tid & 63) == 0) warp_red[tid >> 6] = l2;
    __syncthreads();
    if (tid == 0) {
        float t = 0.f;
        for (int w = 0; w < 16; ++w) t += warp_red[w];
        sh_l2 = t;
        sh_k = 8191; sh_prefix = 0u;
        sh_cle = 0u; sh_minAbove = 0xFFFFFFFFu;
    }
    __syncthreads();

    // --- radix select order stat 8191 (margins >= 0 -> uint order ok) ---
    for (int shift = 24; shift >= 0; shift -= 8) {
        if (tid < 256) hist[tid] = 0u;
        __syncthreads();
        const unsigned prefix = sh_prefix;
        const unsigned mask = (shift == 24) ? 0u : (0xFFFFFFFFu << (shift + 8));
        for (int i = tid; i < NROWS; i += 1024) {
            const unsigned key = __float_as_uint(margins[i]);
            if (((key ^ prefix) & mask) == 0u)
                atomicAdd(&hist[(key >> shift) & 255u], 1u);
        }
        __syncthreads();
        if (tid == 0) {
            int kk = sh_k;
            unsigned cum = 0; int d = 0;
            for (; d < 256; ++d) {
                const unsigned c = hist[d];
                if (cum + c > (unsigned)kk) break;
                cum += c;
            }
            sh_prefix = prefix | ((unsigned)d << shift);
            sh_k = kk - (int)cum;
        }
        __syncthreads();
    }
    const unsigned p1u = sh_prefix;

    // --- one pass: count(<= p1) and min(> p1) -> rank 8192 value ---
    unsigned lc = 0, lmin = 0xFFFFFFFFu;
    for (int i = tid; i < NROWS; i += 1024) {
        const unsigned key = __float_as_uint(margins[i]);
        if (key <= p1u) ++lc; else lmin = min(lmin, key);
    }
    #pragma unroll
    for (int m = 1; m < 64; m <<= 1) {
        lc += __shfl_xor(lc, m);
        lmin = min(lmin, (unsigned)__shfl_xor((int)lmin, m));
    }
    if ((tid & 63) == 0) {
        atomicAdd(&sh_cle, lc);
        atomicMin(&sh_minAbove, lmin);
    }
    __syncthreads();
    const float p1 = __uint_as_float(p1u);
    const float p2 = (sh_cle >= 8193u) ? p1 : __uint_as_float(sh_minAbove);
    const float margin = p1 + 0.75f * (p2 - p1);

    // --- loss sum ---
    float ssum = 0.f;
    for (int i = tid; i < NROWS; i += 1024) {
        const float t = dd[i] + margin;
        ssum += (t > 0.f) ? t : 0.f;
    }
    #pragma unroll
    for (int m = 1; m < 64; m <<= 1) ssum += __shfl_xor(ssum, m);
    if ((tid & 63) == 0) warp_red[tid >> 6] = ssum;
    __syncthreads();
    if (tid == 0) {
        float S = 0.f;
        for (int w = 0; w < 16; ++w) S += warp_red[w];
        out[0] = S / (float)NROWS + 1e-3f * sh_l2 / (float)NROWS;
    }
}

extern "C" void kernel_launch(void* const* d_in, const int* in_sizes, int n_in,
                              void* d_out, int out_size, void* d_ws, size_t ws_size,
                              hipStream_t stream) {
    (void)in_sizes; (void)n_in; (void)out_size; (void)ws_size;
    const float* item = (const float*)d_in[0];
    const float* pos  = (const float*)d_in[1];
    const float* neg  = (const float*)d_in[2];
    const float* W1   = (const float*)d_in[3];
    const float* b1   = (const float*)d_in[4];
    const float* gam  = (const float*)d_in[5];
    const float* bet  = (const float*)d_in[6];
    const float* rmu  = (const float*)d_in[7];
    const float* rvr  = (const float*)d_in[8];
    const float* W2   = (const float*)d_in[9];
    const float* b2   = (const float*)d_in[10];

    char* ws = (char*)d_ws;
    unsigned short* h = (unsigned short*)ws;
    size_t off = (size_t)M3 * HIDD * sizeof(unsigned short);
    unsigned short* W1bf = (unsigned short*)(ws + off); off += (size_t)HIDD * DIM * 2;
    unsigned short* W2bf = (unsigned short*)(ws + off); off += (size_t)DIM * HIDD * 2;
    float* pdp = (float*)(ws + off); off += (size_t)16 * NROWS * 4;
    float* pdn = (float*)(ws + off); off += (size_t)16 * NROWS * 4;
    float* pl2 = (float*)(ws + off); off += (size_t)2048 * 4;
    float* margins = (float*)(ws + off); off += (size_t)NROWS * 4;
    float* dd = (float*)(ws + off); off += (size_t)NROWS * 4;

    cvt_kernel<<<dim3((HIDD*DIM/4 + 255)/256), 256, 0, stream>>>(W1, W1bf, HIDD*DIM/4);
    cvt_kernel<<<dim3((DIM*HIDD/4 + 255)/256), 256, 0, stream>>>(W2, W2bf, DIM*HIDD/4);
    gemm1_mfma<<<dim3(3072), 256, 0, stream>>>(
        item, pos, neg, W1bf, b1, gam, bet, rmu, rvr, h);
    gemm2_mfma<<<dim3(2048), 512, 0, stream>>>(
        h, W2bf, b2, pdp, pdn, pl2);
    margins_kernel<<<dim3(NROWS/256), 256, 0, stream>>>(pdp, pdn, margins, dd);
    final_kernel<<<1, 1024, 0, stream>>>(pl2, 2048, margins, dd, (float*)d_out);
}